// Round 1
// baseline (852.415 us; speedup 1.0000x reference)
//
#include <hip/hip_runtime.h>
#include <hip/hip_bf16.h>

// Problem constants
#define BB 32
#define LQ 18
#define LK 4096
#define DD 768
#define SCALE 0.03608439182435161f  // 1/sqrt(768)

// Workspace layout (bytes):
//   P       : [32][18][4096] fp32   @ 0        (9,437,184 B)
//   partial : [32][18][64]   fp32   @ 9437184  (147,456 B)  per-wave denom partials
//   wqd     : [32][18]       fp32   @ 9584640  (2,304 B)    W[q]/denom[b][q]
//   flag    : int                   @ 9586944  (4 B)        mask dtype: 1=int32, 0=byte
#define WS_P       0
#define WS_PARTIAL 9437184
#define WS_WQD     9584640
#define WS_FLAG    9586944

// ---------------------------------------------------------------------------
// Mask dtype detection: inputs are identical every call (harness restores
// pristine copies), so this is deterministic and graph-capture safe.
// int32 0/1 values => bytes at (i%4 != 0) are all zero. bool bytes => ~50% ones.
__global__ void detect_kernel(const unsigned char* __restrict__ m,
                              int* __restrict__ flag) {
    __shared__ int cnt;
    if (threadIdx.x == 0) cnt = 0;
    __syncthreads();
    int c = 0;
    for (int i = threadIdx.x; i < 16384; i += 256) {
        if ((i & 3) != 0 && m[i] != 0) c = 1;
    }
    if (c) atomicAdd(&cnt, 1);
    __syncthreads();
    if (threadIdx.x == 0) *flag = (cnt == 0) ? 1 : 0;
}

// ---------------------------------------------------------------------------
// Kernel 1: scores + masked exp + per-wave denominator partials.
// Each lane owns one K row (k = chunk*256 + tid); Q reads are wave-uniform
// (b, q, d all uniform) -> scalar loads; 18 fp32 accumulators per lane.
__global__ __launch_bounds__(256, 2) void qk_softmax_kernel(
    const float* __restrict__ Qg, const float* __restrict__ Kg,
    const void* __restrict__ maskg, const int* __restrict__ flag,
    float* __restrict__ P, float* __restrict__ partial) {
    const int chunk = blockIdx.x;   // 0..15
    const int b     = blockIdx.y;   // 0..31
    const int tid   = threadIdx.x;
    const int k     = chunk * 256 + tid;

    const float* Kb = Kg + ((size_t)b * LK + k) * DD;
    const float* Qb = Qg + (size_t)b * LQ * DD;

    float acc[LQ];
#pragma unroll
    for (int q = 0; q < LQ; ++q) acc[q] = 0.0f;

    for (int d = 0; d < DD; d += 4) {
        const float4 kv = *(const float4*)(Kb + d);
#pragma unroll
        for (int q = 0; q < LQ; ++q) {
            const float4 qv = *(const float4*)(Qb + q * DD + d);
            acc[q] += qv.x * kv.x;
            acc[q] += qv.y * kv.y;
            acc[q] += qv.z * kv.z;
            acc[q] += qv.w * kv.w;
        }
    }

    const int isI32 = *flag;
    const unsigned char* m8  = (const unsigned char*)maskg;
    const int*           m32 = (const int*)maskg;

    float p[LQ];
#pragma unroll
    for (int q = 0; q < LQ; ++q) {
        const size_t idx = ((size_t)b * LQ + q) * LK + k;
        const int msk = isI32 ? m32[idx] : (int)m8[idx];
        // reference: where(mask, -1e9, s) then softmax  =>  masked prob = 0
        const float pv = msk ? 0.0f : __expf(acc[q] * SCALE);
        p[q] = pv;
        P[idx] = pv;
    }

    // wave-level reduction of denominator partials (deterministic, no atomics)
    const int lane = tid & 63;
    const int wv   = tid >> 6;  // 0..3
#pragma unroll
    for (int q = 0; q < LQ; ++q) {
        float s = p[q];
#pragma unroll
        for (int off = 32; off > 0; off >>= 1) s += __shfl_xor(s, off, 64);
        if (lane == 0)
            partial[((size_t)b * LQ + q) * 64 + (chunk * 4 + wv)] = s;
    }
}

// ---------------------------------------------------------------------------
// Kernel 2: reduce 64 per-wave partials -> wqd[b][q] = W[q]/denom[b][q]
__global__ void denom_kernel(const float* __restrict__ partial,
                             const float* __restrict__ Wg,
                             float* __restrict__ wqd) {
    const int b = blockIdx.x;
    const int q = threadIdx.x;
    if (q < LQ) {
        const float* pp = partial + ((size_t)b * LQ + q) * 64;
        float s = 0.0f;
#pragma unroll
        for (int w = 0; w < 64; ++w) s += pp[w];
        wqd[b * LQ + q] = Wg[q] / s;
    }
}

// ---------------------------------------------------------------------------
// Kernel 3: attn_fc[b,k] = sum_q P[b,q,k]*wqd[b,q]; context[b,d] += af*V[b,k,d]
// Phase A: thread t <-> row k0+t (coalesced P reads), af -> LDS + d_out.
// Phase B: lanes over d (perfectly coalesced V), af broadcast from LDS.
__global__ __launch_bounds__(256, 2) void fc_context_kernel(
    const float* __restrict__ P, const float* __restrict__ Vg,
    const float* __restrict__ wqd, float* __restrict__ ctx_out,
    float* __restrict__ af_out) {
    const int chunk = blockIdx.x;   // 0..15
    const int b     = blockIdx.y;
    const int tid   = threadIdx.x;
    const int k0    = chunk * 256;

    __shared__ float af_s[256];

    {
        const int k = k0 + tid;
        float af = 0.0f;
#pragma unroll
        for (int q = 0; q < LQ; ++q) {
            af += P[((size_t)b * LQ + q) * LK + k] * wqd[b * LQ + q];
        }
        af_s[tid] = af;
        af_out[(size_t)b * LK + k] = af;
    }
    __syncthreads();

    float c0 = 0.0f, c1 = 0.0f, c2 = 0.0f;
    const float* Vb = Vg + ((size_t)b * LK + k0) * DD;
#pragma unroll 4
    for (int j = 0; j < 256; ++j) {
        const float a   = af_s[j];
        const float* vr = Vb + (size_t)j * DD;
        c0 += a * vr[tid];
        c1 += a * vr[tid + 256];
        c2 += a * vr[tid + 512];
    }
    atomicAdd(&ctx_out[b * DD + tid],       c0);
    atomicAdd(&ctx_out[b * DD + tid + 256], c1);
    atomicAdd(&ctx_out[b * DD + tid + 512], c2);
}

// ---------------------------------------------------------------------------
extern "C" void kernel_launch(void* const* d_in, const int* in_sizes, int n_in,
                              void* d_out, int out_size, void* d_ws, size_t ws_size,
                              hipStream_t stream) {
    const float* Qg   = (const float*)d_in[0];
    const float* Kg   = (const float*)d_in[1];
    const float* Vg   = (const float*)d_in[2];
    const void*  mask = d_in[3];
    const float* Wg   = (const float*)d_in[4];

    // outputs: context [32,1,768] then attn_fc [32,4096,1], both fp32
    float* ctx_out = (float*)d_out;
    float* af_out  = (float*)d_out + BB * DD;

    char*  ws      = (char*)d_ws;
    float* P       = (float*)(ws + WS_P);
    float* partial = (float*)(ws + WS_PARTIAL);
    float* wqd     = (float*)(ws + WS_WQD);
    int*   flag    = (int*)(ws + WS_FLAG);

    // context region accumulated via atomics -> zero it (memset node is
    // graph-capture safe). attn_fc region is fully overwritten, no memset.
    hipMemsetAsync(d_out, 0, BB * DD * sizeof(float), stream);

    detect_kernel<<<1, 256, 0, stream>>>((const unsigned char*)mask, flag);
    qk_softmax_kernel<<<dim3(16, BB), 256, 0, stream>>>(Qg, Kg, mask, flag, P, partial);
    denom_kernel<<<BB, 64, 0, stream>>>(partial, Wg, wqd);
    fc_context_kernel<<<dim3(16, BB), 256, 0, stream>>>(P, Vg, wqd, ctx_out, af_out);
}